// Round 1
// baseline (250.845 us; speedup 1.0000x reference)
//
#include <hip/hip_runtime.h>
#include <hip/hip_fp16.h>

#define DM 128
#define NHEADS 8
#define MAXDEG 64
#define SROW 136   // LDS row stride in halves: 128+8 pad (2-way bank alias = free)

typedef _Float16 half8 __attribute__((ext_vector_type(8)));
typedef _Float16 half2v __attribute__((ext_vector_type(2)));
typedef float floatx4 __attribute__((ext_vector_type(4)));

union H8 { half8 v; half2v h2[4]; };

// ================= standalone CSR build =================
// Runs AFTER proj (own kernel): with the L2 to itself, the ushort csr_dst
// array (6.4 MB = 800 KB/XCD) stays L2-resident, so the 800k random 2B
// writes coalesce in L2 instead of each evicting a dirty 64B line, and the
// array is L2-hot for attn_fused which launches next.
__global__ __launch_bounds__(256) void csr_build(
    const int* __restrict__ nsrc, const int* __restrict__ ndst,
    int* __restrict__ cnt, unsigned short* __restrict__ csr_dst, int E) {
  int tid = threadIdx.x;
  int ebase = blockIdx.x * 2048;
  int s[8], d[8];
#pragma unroll
  for (int j = 0; j < 8; j++) {
    int e = ebase + j * 256 + tid;
    s[j] = (e < E) ? nsrc[e] : -1;
    d[j] = (e < E) ? ndst[e] : 0;
  }
#pragma unroll
  for (int j = 0; j < 8; j++) {
    if (s[j] >= 0) {
      int p = atomicAdd(&cnt[s[j]], 1);
      if (p < MAXDEG) csr_dst[(size_t)s[j] * MAXDEG + p] = (unsigned short)d[j];
    }
  }
}

// ================= pure projection GEMM =================
// X(Mx128,f32) @ Wcat^T(576x128) with inline f32->f16 W conversion.
// one block = 128 M-rows x all 576 N-cols (9 chunks of 64).
// chunk pairs: 0,1->Q  2,3->K(KV lo)  4,5->V(KV hi)  6,7->sigmoid gate  8->bias cols 512..519
// B-chunk is prefetched to registers during the previous chunk's MFMA+epilogue
// (T14 issue-early/write-late) so the barrier-serialized per-chunk critical
// path no longer contains the global-load latency.
__device__ __forceinline__ void prefetch_B(
    int tid, int c, const float* __restrict__ Wqkv,
    const float* __restrict__ Wgate, const float* __restrict__ wbias,
    float4 pf[4][2]) {
#pragma unroll
  for (int i = 0; i < 4; i++) {
    int u = tid + i * 256;           // 0..1023
    int r = u >> 4;                  // 0..63
    int cc = (u & 15) * 8;
    int grow = c * 64 + r;
    const float* src = nullptr;
    if (grow < 384)      src = Wqkv + (size_t)grow * 128 + cc;
    else if (grow < 512) src = Wgate + (size_t)(grow - 384) * 128 + cc;
    else if (grow < 520) src = wbias + (size_t)(grow - 512) * 128 + cc;
    if (src) {
      pf[i][0] = ((const float4*)src)[0];
      pf[i][1] = ((const float4*)src)[1];
    } else {
      pf[i][0] = make_float4(0.f, 0.f, 0.f, 0.f);
      pf[i][1] = make_float4(0.f, 0.f, 0.f, 0.f);
    }
  }
}

__global__ __launch_bounds__(256) void proj_gemm(
    const float* __restrict__ X, const float* __restrict__ Wqkv,
    const float* __restrict__ Wgate, const float* __restrict__ wbias,
    const float* __restrict__ b_gate,
    _Float16* __restrict__ Q, _Float16* __restrict__ KV,
    _Float16* __restrict__ gate, float* __restrict__ bias, int M) {
  __shared__ _Float16 As[128 * SROW];
  __shared__ _Float16 Bs[64 * SROW];
  int tid = threadIdx.x;
  int m0 = blockIdx.x * 128;

  // prefetch chunk 0's B while A stages (loads in flight under the A-store burst)
  float4 pf[4][2];
  prefetch_B(tid, 0, Wqkv, Wgate, wbias, pf);

  // stage A (fp32 -> fp16): 128 rows x 128 cols
#pragma unroll
  for (int i = 0; i < 4; i++) {
    int u = tid + i * 256;           // 0..1023
    int r = u >> 3;
    int cc = (u & 7) * 16;
    int gr = m0 + r;
    float4 f0, f1, f2, f3;
    if (gr < M) {
      const float4* src = (const float4*)(X + (size_t)gr * 128 + cc);
      f0 = src[0]; f1 = src[1]; f2 = src[2]; f3 = src[3];
    } else {
      f0 = f1 = f2 = f3 = make_float4(0.f, 0.f, 0.f, 0.f);
    }
    half8 h0 = {(_Float16)f0.x, (_Float16)f0.y, (_Float16)f0.z, (_Float16)f0.w,
                (_Float16)f1.x, (_Float16)f1.y, (_Float16)f1.z, (_Float16)f1.w};
    half8 h1 = {(_Float16)f2.x, (_Float16)f2.y, (_Float16)f2.z, (_Float16)f2.w,
                (_Float16)f3.x, (_Float16)f3.y, (_Float16)f3.z, (_Float16)f3.w};
    *(half8*)(As + r * SROW + cc) = h0;
    *(half8*)(As + r * SROW + cc + 8) = h1;
  }

  int wid = tid >> 6, lane = tid & 63;
  int quad = lane >> 4, l16 = lane & 15;
  int mw = wid * 32;                 // wave owns 32 M-rows

  for (int c = 0; c < 9; c++) {
    __syncthreads();                 // A ready (c=0) / previous chunk's Bs readers done
    // write back prefetched B chunk (f32 regs -> f16 LDS)
#pragma unroll
    for (int i = 0; i < 4; i++) {
      int u = tid + i * 256;
      int r = u >> 4;
      int cc = (u & 15) * 8;
      half8 h = {(_Float16)pf[i][0].x, (_Float16)pf[i][0].y,
                 (_Float16)pf[i][0].z, (_Float16)pf[i][0].w,
                 (_Float16)pf[i][1].x, (_Float16)pf[i][1].y,
                 (_Float16)pf[i][1].z, (_Float16)pf[i][1].w};
      *(half8*)(Bs + r * SROW + cc) = h;
    }
    if (c < 8) prefetch_B(tid, c + 1, Wqkv, Wgate, wbias, pf);  // issue-early
    __syncthreads();

    floatx4 acc[2][4] = {};
#pragma unroll
    for (int kc = 0; kc < 4; kc++) {
      int ko = kc * 32 + quad * 8;
      half8 a0 = *(const half8*)(As + (mw + l16) * SROW + ko);
      half8 a1 = *(const half8*)(As + (mw + 16 + l16) * SROW + ko);
      half8 b[4];
#pragma unroll
      for (int ni = 0; ni < 4; ni++)
        b[ni] = *(const half8*)(Bs + (ni * 16 + l16) * SROW + ko);
#pragma unroll
      for (int ni = 0; ni < 4; ni++) {
        acc[0][ni] = __builtin_amdgcn_mfma_f32_16x16x32_f16(a0, b[ni], acc[0][ni], 0, 0, 0);
        acc[1][ni] = __builtin_amdgcn_mfma_f32_16x16x32_f16(a1, b[ni], acc[1][ni], 0, 0, 0);
      }
    }

    if (c == 8) {                    // bias chunk: only cols 512..519 real
      if (l16 < 8) {
#pragma unroll
        for (int mi = 0; mi < 2; mi++)
#pragma unroll
          for (int r = 0; r < 4; r++) {
            int row = m0 + mw + mi * 16 + quad * 4 + r;
            if (row < M) bias[(size_t)row * 8 + l16] = acc[mi][0][r];
          }
      }
    } else {
      int reg = c >> 1;              // 0:Q 1:K 2:V 3:gate (wave-uniform)
#pragma unroll
      for (int mi = 0; mi < 2; mi++) {
#pragma unroll
        for (int ni = 0; ni < 4; ni++) {
          int colL = (c & 1) * 64 + ni * 16 + l16;   // 0..127 within region
#pragma unroll
          for (int r = 0; r < 4; r++) {
            int row = m0 + mw + mi * 16 + quad * 4 + r;
            if (row >= M) continue;
            float v = acc[mi][ni][r];
            if (reg == 0)      Q[(size_t)row * 128 + colL] = (_Float16)v;
            else if (reg == 1) KV[(size_t)row * 256 + colL] = (_Float16)v;
            else if (reg == 2) KV[(size_t)row * 256 + 128 + colL] = (_Float16)v;
            else gate[(size_t)row * 128 + colL] =
                   (_Float16)(1.0f / (1.0f + __expf(-(v + b_gate[colL]))));
          }
        }
      }
    }
  }
}

// ================= final GEMM: gated16(Mx128) @ Wo^T(128x128,f32->f16 inline) -> out(f32) =====
__global__ __launch_bounds__(256) void final_gemm_mfma(
    const _Float16* __restrict__ A, const float* __restrict__ Wo,
    float* __restrict__ C, int M) {
  __shared__ _Float16 As[128 * SROW];
  __shared__ _Float16 Bs[64 * SROW];
  int tid = threadIdx.x;
  int m0 = blockIdx.x * 128, n0 = blockIdx.y * 64;
#pragma unroll
  for (int i = 0; i < 8; i++) {
    int u = tid + i * 256;
    int r = u >> 4;
    int cc = (u & 15) * 8;
    int gr = m0 + r;
    int4 val = make_int4(0, 0, 0, 0);
    if (gr < M) val = *(const int4*)(A + (size_t)gr * 128 + cc);
    *(int4*)(As + r * SROW + cc) = val;
  }
#pragma unroll
  for (int i = 0; i < 4; i++) {
    int u = tid + i * 256;
    int r = u >> 4;
    int cc = (u & 15) * 8;
    const float* src = Wo + (size_t)(n0 + r) * 128 + cc;
    float4 f0 = ((const float4*)src)[0];
    float4 f1 = ((const float4*)src)[1];
    half8 h = {(_Float16)f0.x, (_Float16)f0.y, (_Float16)f0.z, (_Float16)f0.w,
               (_Float16)f1.x, (_Float16)f1.y, (_Float16)f1.z, (_Float16)f1.w};
    *(half8*)(Bs + r * SROW + cc) = h;
  }
  __syncthreads();

  int wid = tid >> 6, lane = tid & 63;
  int quad = lane >> 4, l16 = lane & 15;
  int mw = (wid >> 1) * 64;
  int nw = (wid & 1) * 32;

  floatx4 acc[4][2] = {};
#pragma unroll
  for (int kc = 0; kc < 4; kc++) {
    int ko = kc * 32 + quad * 8;
    half8 a[4], b[2];
#pragma unroll
    for (int mi = 0; mi < 4; mi++)
      a[mi] = *(const half8*)(As + (mw + mi * 16 + l16) * SROW + ko);
#pragma unroll
    for (int ni = 0; ni < 2; ni++)
      b[ni] = *(const half8*)(Bs + (nw + ni * 16 + l16) * SROW + ko);
#pragma unroll
    for (int mi = 0; mi < 4; mi++)
#pragma unroll
      for (int ni = 0; ni < 2; ni++)
        acc[mi][ni] = __builtin_amdgcn_mfma_f32_16x16x32_f16(a[mi], b[ni], acc[mi][ni], 0, 0, 0);
  }
#pragma unroll
  for (int mi = 0; mi < 4; mi++) {
#pragma unroll
    for (int ni = 0; ni < 2; ni++) {
      int col = n0 + nw + ni * 16 + l16;
#pragma unroll
      for (int r = 0; r < 4; r++) {
        int row = m0 + mw + mi * 16 + quad * 4 + r;
        if (row >= M) continue;
        C[(size_t)row * 128 + col] = acc[mi][ni][r];
      }
    }
  }
}

// ============ fused attention: one wave/node, quarter-wave per edge, prefetch depth 2 ========
// lane = qtr*16 + l16; lane owns channels [l16*8, l16*8+8); head = l16>>1
__global__ __launch_bounds__(256) void attn_fused(
    const int* __restrict__ cnt, const unsigned short* __restrict__ csr_dst,
    const _Float16* __restrict__ Q, const _Float16* __restrict__ KV,
    const float* __restrict__ bias, const _Float16* __restrict__ gate,
    _Float16* __restrict__ gated, int N) {
  int wave = threadIdx.x >> 6, lane = threadIdx.x & 63;
  int n = blockIdx.x * 4 + wave;
  if (n >= N) return;
  int deg = cnt[n];
  if (deg > MAXDEG) deg = MAXDEG;
  int qtr = lane >> 4, l16 = lane & 15;
  int ch0 = l16 * 8;

  int dstv = csr_dst[(size_t)n * MAXDEG + lane];   // coalesced; garbage beyond deg (guarded)

  H8 qu; qu.v = *(const half8*)(Q + (size_t)n * DM + ch0);
  float bias_h = bias[(size_t)n * NHEADS + (l16 >> 1)];

  float acc[8] = {};
  float den = 0.f;
  int iters = (deg + 3) >> 2;        // 4 edges per iteration (one per quarter-wave)

  H8 k0, v0, k1, v1;
  k0.v = half8{}; v0.v = half8{}; k1.v = half8{}; v1.v = half8{};
  bool b0 = false, b1 = false;
  if (0 < iters) {
    int e = qtr;
    b0 = e < deg;
    int d = __shfl(dstv, e);
    d = b0 ? d : 0;
    const _Float16* kvp = KV + (size_t)d * 256 + ch0;
    k0.v = *(const half8*)kvp;
    v0.v = *(const half8*)(kvp + 128);
  }
  if (1 < iters) {
    int e = 4 + qtr;
    b1 = e < deg;
    int d = __shfl(dstv, e);
    d = b1 ? d : 0;
    const _Float16* kvp = KV + (size_t)d * 256 + ch0;
    k1.v = *(const half8*)kvp;
    v1.v = *(const half8*)(kvp + 128);
  }

  for (int it = 0; it < iters; it++) {
    H8 k2, v2;
    k2.v = half8{}; v2.v = half8{};
    bool b2 = false;
    if (it + 2 < iters) {            // wave-uniform branch
      int e = (it + 2) * 4 + qtr;    // <= 63 since deg <= 64
      b2 = e < deg;
      int d = __shfl(dstv, e);
      d = b2 ? d : 0;
      const _Float16* kvp = KV + (size_t)d * 256 + ch0;
      k2.v = *(const half8*)kvp;
      v2.v = *(const half8*)(kvp + 128);
    }
    // score: mixed-precision dot (v_dot2_f32_f16), then 16-channel head reduce
    float p = 0.f;
#pragma unroll
    for (int j = 0; j < 4; j++)
      p = __builtin_amdgcn_fdot2(qu.h2[j], k0.h2[j], p, false);
    p += __shfl_xor(p, 1);
    float w = __expf(p * 0.25f + bias_h);   // scale=1/sqrt(16); scores O(10), fp32-safe
    if (!b0) w = 0.f;
    den += w;
#pragma unroll
    for (int j = 0; j < 8; j++) acc[j] = fmaf(w, (float)v0.v[j], acc[j]);
    k0 = k1; v0 = v1; b0 = b1;
    k1 = k2; v1 = v2; b1 = b2;
  }
  // combine the four quarter-wave partials (butterfly)
#pragma unroll
  for (int j = 0; j < 8; j++) acc[j] += __shfl_xor(acc[j], 16);
#pragma unroll
  for (int j = 0; j < 8; j++) acc[j] += __shfl_xor(acc[j], 32);
  den += __shfl_xor(den, 16);
  den += __shfl_xor(den, 32);

  if (qtr == 0) {
    float inv = 1.0f / (den + 1e-12f);
    half8 gv = *(const half8*)(gate + (size_t)n * DM + ch0);
    half8 o;
#pragma unroll
    for (int j = 0; j < 8; j++) o[j] = (_Float16)(acc[j] * inv * (float)gv[j]);
    *(half8*)(gated + (size_t)n * DM + ch0) = o;
  }
}

extern "C" void kernel_launch(void* const* d_in, const int* in_sizes, int n_in,
                              void* d_out, int out_size, void* d_ws, size_t ws_size,
                              hipStream_t stream) {
  const float* X     = (const float*)d_in[0];
  const float* Wqkv  = (const float*)d_in[1];
  const float* wbias = (const float*)d_in[2];
  const float* Wgate = (const float*)d_in[3];
  const float* bgate = (const float*)d_in[4];
  const float* Wo    = (const float*)d_in[5];
  const int*   nsrc  = (const int*)d_in[6];
  const int*   ndst  = (const int*)d_in[7];
  int N = in_sizes[0] / 128;
  int E = in_sizes[6];
  float* out = (float*)d_out;

  char* p = (char*)d_ws;
  _Float16* Q16     = (_Float16*)p; p += (size_t)N * 128 * sizeof(_Float16);
  _Float16* KV16    = (_Float16*)p; p += (size_t)N * 256 * sizeof(_Float16);
  _Float16* gate16  = (_Float16*)p; p += (size_t)N * 128 * sizeof(_Float16);
  _Float16* gated16 = (_Float16*)p; p += (size_t)N * 128 * sizeof(_Float16);
  float* bias       = (float*)p;    p += (size_t)N * 8 * sizeof(float);
  int* cnt          = (int*)p;      p += (size_t)N * sizeof(int);
  unsigned short* csr_dst = (unsigned short*)p;
  p += (size_t)N * MAXDEG * sizeof(unsigned short);

  hipMemsetAsync(cnt, 0, (size_t)N * sizeof(int), stream);

  int P = (N + 127) / 128;                 // proj blocks
  proj_gemm<<<P, 256, 0, stream>>>(X, Wqkv, Wgate, wbias, bgate,
                                   Q16, KV16, gate16, bias, N);

  int C = (E + 2047) / 2048;               // csr blocks (2048 edges each)
  csr_build<<<C, 256, 0, stream>>>(nsrc, ndst, cnt, csr_dst, E);

  attn_fused<<<(N + 3) / 4, 256, 0, stream>>>(cnt, csr_dst, Q16, KV16, bias,
                                              gate16, gated16, N);

  dim3 fg((N + 127) / 128, 2);
  final_gemm_mfma<<<fg, 256, 0, stream>>>(gated16, Wo, out, N);
}

// Round 2
// 230.779 us; speedup vs baseline: 1.0869x; 1.0869x over previous
//
#include <hip/hip_runtime.h>
#include <hip/hip_fp16.h>

#define DM 128
#define NHEADS 8
#define MAXDEG 64
#define SROW 136   // LDS row stride in halves: 128+8 pad (2-way bank alias = free)

typedef _Float16 half8 __attribute__((ext_vector_type(8)));
typedef _Float16 half2v __attribute__((ext_vector_type(2)));
typedef float floatx4 __attribute__((ext_vector_type(4)));

union H8 { half8 v; half2v h2[4]; };

// ================= fused: proj GEMM blocks [0,P) + CSR-build blocks [P,P+C) =================
// Re-fused: stream-serialization of separate kernels cost ~35us (round-1 evidence);
// CSR atomic latency hides under co-resident proj blocks' MFMA.
// proj: X(Mx128,f32) @ Wcat^T(576x128), inline f32->f16 W conversion, B-chunk prefetched
// to registers during previous chunk's MFMA+epilogue (issue-early/write-late).
// chunk pairs: 0,1->Q  2,3->K(KV lo)  4,5->V(KV hi)  6,7->sigmoid gate  8->bias cols 512..519
__device__ __forceinline__ void prefetch_B(
    int tid, int c, const float* __restrict__ Wqkv,
    const float* __restrict__ Wgate, const float* __restrict__ wbias,
    float4 pf[4][2]) {
#pragma unroll
  for (int i = 0; i < 4; i++) {
    int u = tid + i * 256;           // 0..1023
    int r = u >> 4;                  // 0..63
    int cc = (u & 15) * 8;
    int grow = c * 64 + r;
    const float* src = nullptr;
    if (grow < 384)      src = Wqkv + (size_t)grow * 128 + cc;
    else if (grow < 512) src = Wgate + (size_t)(grow - 384) * 128 + cc;
    else if (grow < 520) src = wbias + (size_t)(grow - 512) * 128 + cc;
    if (src) {
      pf[i][0] = ((const float4*)src)[0];
      pf[i][1] = ((const float4*)src)[1];
    } else {
      pf[i][0] = make_float4(0.f, 0.f, 0.f, 0.f);
      pf[i][1] = make_float4(0.f, 0.f, 0.f, 0.f);
    }
  }
}

__global__ __launch_bounds__(256) void proj_csr(
    const float* __restrict__ X, const float* __restrict__ Wqkv,
    const float* __restrict__ Wgate, const float* __restrict__ wbias,
    const float* __restrict__ b_gate,
    const int* __restrict__ nsrc, const int* __restrict__ ndst,
    int* __restrict__ cnt, unsigned short* __restrict__ csr_dst,
    _Float16* __restrict__ Q, _Float16* __restrict__ KV,
    _Float16* __restrict__ gate, float* __restrict__ bias,
    int M, int E, int P) {
  __shared__ _Float16 As[128 * SROW];
  __shared__ _Float16 Bs[64 * SROW];
  int tid = threadIdx.x;
  int bid = blockIdx.x;

  if (bid >= P) {
    // ---------------- CSR build role ----------------
    int ebase = (bid - P) * 8192;
    for (int g = 0; g < 4; g++) {
      int s[8], d[8];
#pragma unroll
      for (int j = 0; j < 8; j++) {
        int e = ebase + (g * 8 + j) * 256 + tid;
        s[j] = (e < E) ? __builtin_nontemporal_load(nsrc + e) : -1;
        d[j] = (e < E) ? __builtin_nontemporal_load(ndst + e) : 0;
      }
#pragma unroll
      for (int j = 0; j < 8; j++) {
        if (s[j] >= 0) {
          int p = atomicAdd(&cnt[s[j]], 1);
          if (p < MAXDEG) csr_dst[(size_t)s[j] * MAXDEG + p] = (unsigned short)d[j];
        }
      }
    }
    return;
  }

  // ---------------- projection GEMM role ----------------
  int m0 = bid * 128;

  // prefetch chunk 0's B while A stages (loads in flight under the A-store burst)
  float4 pf[4][2];
  prefetch_B(tid, 0, Wqkv, Wgate, wbias, pf);

  // stage A (fp32 -> fp16): 128 rows x 128 cols
#pragma unroll
  for (int i = 0; i < 4; i++) {
    int u = tid + i * 256;           // 0..1023
    int r = u >> 3;
    int cc = (u & 7) * 16;
    int gr = m0 + r;
    float4 f0, f1, f2, f3;
    if (gr < M) {
      const float4* src = (const float4*)(X + (size_t)gr * 128 + cc);
      f0 = src[0]; f1 = src[1]; f2 = src[2]; f3 = src[3];
    } else {
      f0 = f1 = f2 = f3 = make_float4(0.f, 0.f, 0.f, 0.f);
    }
    half8 h0 = {(_Float16)f0.x, (_Float16)f0.y, (_Float16)f0.z, (_Float16)f0.w,
                (_Float16)f1.x, (_Float16)f1.y, (_Float16)f1.z, (_Float16)f1.w};
    half8 h1 = {(_Float16)f2.x, (_Float16)f2.y, (_Float16)f2.z, (_Float16)f2.w,
                (_Float16)f3.x, (_Float16)f3.y, (_Float16)f3.z, (_Float16)f3.w};
    *(half8*)(As + r * SROW + cc) = h0;
    *(half8*)(As + r * SROW + cc + 8) = h1;
  }

  int wid = tid >> 6, lane = tid & 63;
  int quad = lane >> 4, l16 = lane & 15;
  int mw = wid * 32;                 // wave owns 32 M-rows

  for (int c = 0; c < 9; c++) {
    __syncthreads();                 // A ready (c=0) / previous chunk's Bs readers done
    // write back prefetched B chunk (f32 regs -> f16 LDS)
#pragma unroll
    for (int i = 0; i < 4; i++) {
      int u = tid + i * 256;
      int r = u >> 4;
      int cc = (u & 15) * 8;
      half8 h = {(_Float16)pf[i][0].x, (_Float16)pf[i][0].y,
                 (_Float16)pf[i][0].z, (_Float16)pf[i][0].w,
                 (_Float16)pf[i][1].x, (_Float16)pf[i][1].y,
                 (_Float16)pf[i][1].z, (_Float16)pf[i][1].w};
      *(half8*)(Bs + r * SROW + cc) = h;
    }
    if (c < 8) prefetch_B(tid, c + 1, Wqkv, Wgate, wbias, pf);  // issue-early
    __syncthreads();

    floatx4 acc[2][4] = {};
#pragma unroll
    for (int kc = 0; kc < 4; kc++) {
      int ko = kc * 32 + quad * 8;
      half8 a0 = *(const half8*)(As + (mw + l16) * SROW + ko);
      half8 a1 = *(const half8*)(As + (mw + 16 + l16) * SROW + ko);
      half8 b[4];
#pragma unroll
      for (int ni = 0; ni < 4; ni++)
        b[ni] = *(const half8*)(Bs + (ni * 16 + l16) * SROW + ko);
#pragma unroll
      for (int ni = 0; ni < 4; ni++) {
        acc[0][ni] = __builtin_amdgcn_mfma_f32_16x16x32_f16(a0, b[ni], acc[0][ni], 0, 0, 0);
        acc[1][ni] = __builtin_amdgcn_mfma_f32_16x16x32_f16(a1, b[ni], acc[1][ni], 0, 0, 0);
      }
    }

    if (c == 8) {                    // bias chunk: only cols 512..519 real
      if (l16 < 8) {
#pragma unroll
        for (int mi = 0; mi < 2; mi++)
#pragma unroll
          for (int r = 0; r < 4; r++) {
            int row = m0 + mw + mi * 16 + quad * 4 + r;
            if (row < M) bias[(size_t)row * 8 + l16] = acc[mi][0][r];
          }
      }
    } else {
      int reg = c >> 1;              // 0:Q 1:K 2:V 3:gate (wave-uniform)
#pragma unroll
      for (int mi = 0; mi < 2; mi++) {
#pragma unroll
        for (int ni = 0; ni < 4; ni++) {
          int colL = (c & 1) * 64 + ni * 16 + l16;   // 0..127 within region
#pragma unroll
          for (int r = 0; r < 4; r++) {
            int row = m0 + mw + mi * 16 + quad * 4 + r;
            if (row >= M) continue;
            float v = acc[mi][ni][r];
            if (reg == 0)      Q[(size_t)row * 128 + colL] = (_Float16)v;
            else if (reg == 1) KV[(size_t)row * 256 + colL] = (_Float16)v;
            else if (reg == 2) KV[(size_t)row * 256 + 128 + colL] = (_Float16)v;
            else gate[(size_t)row * 128 + colL] =
                   (_Float16)(1.0f / (1.0f + __expf(-(v + b_gate[colL]))));
          }
        }
      }
    }
  }
}

// ================= final GEMM: gated16(Mx128) @ Wo^T(128x128,f32->f16 inline) -> out(f32) =====
__global__ __launch_bounds__(256) void final_gemm_mfma(
    const _Float16* __restrict__ A, const float* __restrict__ Wo,
    float* __restrict__ C, int M) {
  __shared__ _Float16 As[128 * SROW];
  __shared__ _Float16 Bs[64 * SROW];
  int tid = threadIdx.x;
  int m0 = blockIdx.x * 128, n0 = blockIdx.y * 64;
#pragma unroll
  for (int i = 0; i < 8; i++) {
    int u = tid + i * 256;
    int r = u >> 4;
    int cc = (u & 15) * 8;
    int gr = m0 + r;
    int4 val = make_int4(0, 0, 0, 0);
    if (gr < M) val = *(const int4*)(A + (size_t)gr * 128 + cc);
    *(int4*)(As + r * SROW + cc) = val;
  }
#pragma unroll
  for (int i = 0; i < 4; i++) {
    int u = tid + i * 256;
    int r = u >> 4;
    int cc = (u & 15) * 8;
    const float* src = Wo + (size_t)(n0 + r) * 128 + cc;
    float4 f0 = ((const float4*)src)[0];
    float4 f1 = ((const float4*)src)[1];
    half8 h = {(_Float16)f0.x, (_Float16)f0.y, (_Float16)f0.z, (_Float16)f0.w,
               (_Float16)f1.x, (_Float16)f1.y, (_Float16)f1.z, (_Float16)f1.w};
    *(half8*)(Bs + r * SROW + cc) = h;
  }
  __syncthreads();

  int wid = tid >> 6, lane = tid & 63;
  int quad = lane >> 4, l16 = lane & 15;
  int mw = (wid >> 1) * 64;
  int nw = (wid & 1) * 32;

  floatx4 acc[4][2] = {};
#pragma unroll
  for (int kc = 0; kc < 4; kc++) {
    int ko = kc * 32 + quad * 8;
    half8 a[4], b[2];
#pragma unroll
    for (int mi = 0; mi < 4; mi++)
      a[mi] = *(const half8*)(As + (mw + mi * 16 + l16) * SROW + ko);
#pragma unroll
    for (int ni = 0; ni < 2; ni++)
      b[ni] = *(const half8*)(Bs + (nw + ni * 16 + l16) * SROW + ko);
#pragma unroll
    for (int mi = 0; mi < 4; mi++)
#pragma unroll
      for (int ni = 0; ni < 2; ni++)
        acc[mi][ni] = __builtin_amdgcn_mfma_f32_16x16x32_f16(a[mi], b[ni], acc[mi][ni], 0, 0, 0);
  }
#pragma unroll
  for (int mi = 0; mi < 4; mi++) {
#pragma unroll
    for (int ni = 0; ni < 2; ni++) {
      int col = n0 + nw + ni * 16 + l16;
#pragma unroll
      for (int r = 0; r < 4; r++) {
        int row = m0 + mw + mi * 16 + quad * 4 + r;
        if (row >= M) continue;
        C[(size_t)row * 128 + col] = acc[mi][ni][r];
      }
    }
  }
}

// ============ fused attention: one wave/node, quarter-wave per edge ========
// Depth-4 static-slot software pipeline: slot j is refilled 4 iterations ahead,
// so no rotation v_movs and no runtime buffer indexing (would go to scratch).
// For the typical node (deg<=16) ALL KV gathers are issued upfront (max MLP).
// One-shot streams (cnt/csr/Q/bias/gate/gated) use nontemporal hints so the
// 4MB/XCD L2 is reserved for the 25.6MB KV gather working set.
// lane = qtr*16 + l16; lane owns channels [l16*8, l16*8+8); head = l16>>1
__global__ __launch_bounds__(256) void attn_fused(
    const int* __restrict__ cnt, const unsigned short* __restrict__ csr_dst,
    const _Float16* __restrict__ Q, const _Float16* __restrict__ KV,
    const float* __restrict__ bias, const _Float16* __restrict__ gate,
    _Float16* __restrict__ gated, int N) {
  int wave = threadIdx.x >> 6, lane = threadIdx.x & 63;
  int n = blockIdx.x * 4 + wave;
  if (n >= N) return;
  int deg = __builtin_nontemporal_load(cnt + n);
  if (deg > MAXDEG) deg = MAXDEG;
  int qtr = lane >> 4, l16 = lane & 15;
  int ch0 = l16 * 8;

  int dstv = (int)__builtin_nontemporal_load(csr_dst + (size_t)n * MAXDEG + lane);

  H8 qu; qu.v = __builtin_nontemporal_load((const half8*)(Q + (size_t)n * DM + ch0));
  float bias_h = __builtin_nontemporal_load(bias + (size_t)n * NHEADS + (l16 >> 1));

  float acc[8] = {};
  float den = 0.f;
  int iters = (deg + 3) >> 2;        // 4 edges per iteration (one per quarter-wave)

  H8 kb[4], vb[4];
  bool bb[4];
  // prime slots 0..3 with iterations 0..3 (all loads in flight before any compute)
#pragma unroll
  for (int j = 0; j < 4; j++) {
    bb[j] = false;
    kb[j].v = half8{}; vb[j].v = half8{};
    if (j < iters) {                 // wave-uniform
      int e = j * 4 + qtr;
      bb[j] = e < deg;
      int d = __shfl(dstv, e);
      d = bb[j] ? d : 0;
      const _Float16* kvp = KV + (size_t)d * 256 + ch0;
      kb[j].v = *(const half8*)kvp;
      vb[j].v = *(const half8*)(kvp + 128);
    }
  }

  for (int base = 0; base < iters; base += 4) {
#pragma unroll
    for (int j = 0; j < 4; j++) {
      // ---- process slot j (= iteration base+j; bb[j]=false slots contribute 0) ----
      float p = 0.f;
#pragma unroll
      for (int t = 0; t < 4; t++)
        p = __builtin_amdgcn_fdot2(qu.h2[t], kb[j].h2[t], p, false);
      p += __shfl_xor(p, 1);
      float w = __expf(p * 0.25f + bias_h);   // scale=1/sqrt(16); scores O(10), fp32-safe
      if (!bb[j]) w = 0.f;
      den += w;
#pragma unroll
      for (int t = 0; t < 8; t++) acc[t] = fmaf(w, (float)vb[j].v[t], acc[t]);
      // ---- refill slot j with iteration base+4+j (stays in flight 3 iterations) ----
      int idx = base + 4 + j;
      bb[j] = false;
      if (idx < iters) {             // wave-uniform; also guarantees e <= 63 for shfl
        int e = idx * 4 + qtr;
        bb[j] = e < deg;
        int d = __shfl(dstv, e);
        d = bb[j] ? d : 0;
        const _Float16* kvp = KV + (size_t)d * 256 + ch0;
        kb[j].v = *(const half8*)kvp;
        vb[j].v = *(const half8*)(kvp + 128);
      }
    }
  }

  // combine the four quarter-wave partials (butterfly)
#pragma unroll
  for (int j = 0; j < 8; j++) acc[j] += __shfl_xor(acc[j], 16);
#pragma unroll
  for (int j = 0; j < 8; j++) acc[j] += __shfl_xor(acc[j], 32);
  den += __shfl_xor(den, 16);
  den += __shfl_xor(den, 32);

  if (qtr == 0) {
    float inv = 1.0f / (den + 1e-12f);
    half8 gv = __builtin_nontemporal_load((const half8*)(gate + (size_t)n * DM + ch0));
    half8 o;
#pragma unroll
    for (int j = 0; j < 8; j++) o[j] = (_Float16)(acc[j] * inv * (float)gv[j]);
    __builtin_nontemporal_store(o, (half8*)(gated + (size_t)n * DM + ch0));
  }
}

extern "C" void kernel_launch(void* const* d_in, const int* in_sizes, int n_in,
                              void* d_out, int out_size, void* d_ws, size_t ws_size,
                              hipStream_t stream) {
  const float* X     = (const float*)d_in[0];
  const float* Wqkv  = (const float*)d_in[1];
  const float* wbias = (const float*)d_in[2];
  const float* Wgate = (const float*)d_in[3];
  const float* bgate = (const float*)d_in[4];
  const float* Wo    = (const float*)d_in[5];
  const int*   nsrc  = (const int*)d_in[6];
  const int*   ndst  = (const int*)d_in[7];
  int N = in_sizes[0] / 128;
  int E = in_sizes[6];
  float* out = (float*)d_out;

  char* p = (char*)d_ws;
  _Float16* Q16     = (_Float16*)p; p += (size_t)N * 128 * sizeof(_Float16);
  _Float16* KV16    = (_Float16*)p; p += (size_t)N * 256 * sizeof(_Float16);
  _Float16* gate16  = (_Float16*)p; p += (size_t)N * 128 * sizeof(_Float16);
  _Float16* gated16 = (_Float16*)p; p += (size_t)N * 128 * sizeof(_Float16);
  float* bias       = (float*)p;    p += (size_t)N * 8 * sizeof(float);
  int* cnt          = (int*)p;      p += (size_t)N * sizeof(int);
  unsigned short* csr_dst = (unsigned short*)p;
  p += (size_t)N * MAXDEG * sizeof(unsigned short);

  hipMemsetAsync(cnt, 0, (size_t)N * sizeof(int), stream);

  int P = (N + 127) / 128;                 // proj blocks
  int C = (E + 8191) / 8192;               // csr blocks
  proj_csr<<<P + C, 256, 0, stream>>>(X, Wqkv, Wgate, wbias, bgate, nsrc, ndst,
                                      cnt, csr_dst, Q16, KV16, gate16, bias, N, E, P);

  attn_fused<<<(N + 3) / 4, 256, 0, stream>>>(cnt, csr_dst, Q16, KV16, bias,
                                              gate16, gated16, N);

  dim3 fg((N + 127) / 128, 2);
  final_gemm_mfma<<<fg, 256, 0, stream>>>(gated16, Wo, out, N);
}